// Round 6
// baseline (3204.561 us; speedup 1.0000x reference)
//
#include <hip/hip_runtime.h>
#include <math.h>

#define NB 256
#define IMG 256
#define GSZ 64
#define HID 512
#define NSTEP 16
#define KTOT 4608            // 4096 (x) + 512 (Hx)
#define SPLITK 8
#define KCHUNK 576           // KTOT / SPLITK
#define KSTEPS 18            // KCHUNK / 32
#define SP 40                // img-stage / Fw-chunk pitch (u16)
#define TP 72                // t1T / Fh chunk pitch (u16)

typedef unsigned short u16;
typedef __attribute__((ext_vector_type(8))) short s16x8;   // 8 bf16
typedef __attribute__((ext_vector_type(4))) float f32x4;

__device__ inline u16 f2bf(float f) {           // round-to-nearest-even bf16
    unsigned u = __float_as_uint(f);
    unsigned r = u + 0x7fffu + ((u >> 16) & 1u);
    return (u16)(r >> 16);
}
__device__ inline float bf2f(u16 h) { return __uint_as_float((unsigned)h << 16); }
__device__ inline float sigm(float v) { return 1.0f / (1.0f + expf(-v)); }

// software grid barrier: bar[0]=release gen, bar[1..256]=per-block arrive gen.
// Requires all NB blocks resident (guaranteed: LDS 51.8KB -> 3 blk/CU,
// __launch_bounds__(256,2) caps VGPR at 256 -> 2 blk/CU by waves; 256 blocks on 256 CUs).
__device__ inline void gridbar(int* bar, int gen) {
    __threadfence();          // device-scope: make this block's writes visible
    __syncthreads();
    const int b = blockIdx.x, t = threadIdx.x;
    if (b == 0) {
        if (t > 0) {          // thread t watches block t's arrive flag
            while (__hip_atomic_load(&bar[1 + t], __ATOMIC_ACQUIRE,
                                     __HIP_MEMORY_SCOPE_AGENT) < gen)
                __builtin_amdgcn_s_sleep(2);
        }
        __syncthreads();
        if (t == 0)
            __hip_atomic_store(&bar[0], gen, __ATOMIC_RELEASE,
                               __HIP_MEMORY_SCOPE_AGENT);
    } else {
        if (t == 0) {
            __hip_atomic_store(&bar[1 + b], gen, __ATOMIC_RELEASE,
                               __HIP_MEMORY_SCOPE_AGENT);
            while (__hip_atomic_load(&bar[0], __ATOMIC_ACQUIRE,
                                     __HIP_MEMORY_SCOPE_AGENT) < gen)
                __builtin_amdgcn_s_sleep(2);
        }
        __syncthreads();
    }
}

__global__ __launch_bounds__(256, 2) void k_all(
    const float* __restrict__ imgs, const float* __restrict__ W_ih,
    const float* __restrict__ W_hh, const float* __restrict__ b_ih,
    const float* __restrict__ b_hh, const float* __restrict__ W_g,
    const float* __restrict__ b_g,
    int* __restrict__ bar,
    u16* __restrict__ wc_hi, u16* __restrict__ wc_lo,
    u16* __restrict__ xcat_hi, u16* __restrict__ xcat_lo,
    float* __restrict__ part, float* __restrict__ out)
{
    // 51,200 B overlaid static LDS (+ small scratch) -- fits default 64 KB
    __shared__ __align__(16) u16 sm[25600];
    __shared__ float invW[64];
    __shared__ float invA[64];
    __shared__ float red[12];
    // phase-1 overlay
    u16* AstH = sm;            // [256][SP] img chunk hi
    u16* AstL = sm + 10240;    // [256][SP] img chunk lo
    u16* FwcH = sm + 20480;    // [64][SP]  Fw chunk hi
    u16* FwcL = sm + 23040;    // [64][SP]  Fw chunk lo
    // phase-2 overlay
    u16* t1TH = sm;            // [64][TP]  t1T chunk hi
    u16* t1TL = sm + 4608;
    u16* FhcH = sm + 9216;     // [64][TP]  Fh chunk hi
    u16* FhcL = sm + 13824;
    // G-phase overlay
    u16 (*gsm)[128][40] = (u16 (*)[128][40])sm;

    const int b = blockIdx.x, t = threadIdx.x;
    const int lane = t & 63, wv = t >> 6;
    const int fr = lane & 15, kg = lane >> 4;

    // persistent LSTM state: units t and t+256 of batch b
    float hx0 = 0.f, hx1 = 0.f, cx0 = 0.f, cx1 = 0.f;

    // ---------- weight split phase (wc = [W_ih | W_hh] hi/lo) ----------
    {
        const int nchunk = 2048 * KTOT / 4;      // 2,359,296
        for (int c = b * 256 + t; c < nchunk; c += 65536) {
            const int j = c / (KTOT / 4);
            const int k = (c - j * (KTOT / 4)) * 4;
            float4 v;
            if (k < 4096) v = *(const float4*)&W_ih[(size_t)j * 4096 + k];
            else          v = *(const float4*)&W_hh[(size_t)j * 512 + (k - 4096)];
            float f[4] = {v.x, v.y, v.z, v.w};
            u16 hi[4], lo[4];
            #pragma unroll
            for (int i = 0; i < 4; ++i) {
                hi[i] = f2bf(f[i]);
                lo[i] = f2bf(f[i] - bf2f(hi[i]));
            }
            const size_t o = (size_t)j * KTOT + k;
            *(ushort4*)&wc_hi[o] = make_ushort4(hi[0], hi[1], hi[2], hi[3]);
            *(ushort4*)&wc_lo[o] = make_ushort4(lo[0], lo[1], lo[2], lo[3]);
        }
    }
    // first wc read is in G(0), after the first grid barrier

    for (int step = 0; step < NSTEP; ++step) {
        // ========== LSTM update from previous step's partials ==========
        if (step == 0) {
            const size_t o = (size_t)b * KTOT + 4096 + t;
            xcat_hi[o] = 0;       xcat_lo[o] = 0;
            xcat_hi[o + 256] = 0; xcat_lo[o + 256] = 0;
        } else {
            #pragma unroll
            for (int half = 0; half < 2; ++half) {
                const int u = t + half * 256;
                float gi = b_ih[u] + b_hh[u];
                float gf = b_ih[HID + u] + b_hh[HID + u];
                float gg = b_ih[2 * HID + u] + b_hh[2 * HID + u];
                float go = b_ih[3 * HID + u] + b_hh[3 * HID + u];
                const float* pb = part + (size_t)b * 2048;
                #pragma unroll
                for (int kc = 0; kc < SPLITK; ++kc) {
                    const float* p = pb + (size_t)kc * (256 * 2048);
                    gi += p[u];
                    gf += p[HID + u];
                    gg += p[2 * HID + u];
                    go += p[3 * HID + u];
                }
                float co = half ? cx1 : cx0;
                float c = sigm(gf) * co + sigm(gi) * tanhf(gg);
                float h = sigm(go) * tanhf(c);
                if (half) { cx1 = c; hx1 = h; } else { cx0 = c; hx0 = h; }
                u16 hh = f2bf(h);
                xcat_hi[(size_t)b * KTOT + 4096 + u] = hh;
                xcat_lo[(size_t)b * KTOT + 4096 + u] = f2bf(h - bf2f(hh));
            }
        }
        // ========== params: gp = tanh(Hx @ W_g^T + b_g) ==========
        float s0 = hx0 * W_g[t] + hx1 * W_g[t + 256];
        float s1 = hx0 * W_g[HID + t] + hx1 * W_g[HID + t + 256];
        float s2 = hx0 * W_g[2 * HID + t] + hx1 * W_g[2 * HID + t + 256];
        for (int off = 32; off; off >>= 1) {
            s0 += __shfl_xor(s0, off, 64);
            s1 += __shfl_xor(s1, off, 64);
            s2 += __shfl_xor(s2, off, 64);
        }
        __syncthreads();
        if (lane == 0) { red[wv * 3 + 0] = s0; red[wv * 3 + 1] = s1; red[wv * 3 + 2] = s2; }
        __syncthreads();
        s0 = red[0] + red[3] + red[6] + red[9];
        s1 = red[1] + red[4] + red[7] + red[10];
        s2 = red[2] + red[5] + red[8] + red[11];
        const float g0 = tanhf(s0 + b_g[0]);
        const float g1 = tanhf(s1 + b_g[1]);
        const float g2 = tanhf(s2 + b_g[2]);
        const float ad = fabsf(g2);
        const float ch = 127.5f * (g0 + 1.0f);
        const float cw = 127.5f * (g1 + 1.0f);
        const float dl = 4.0f * (1.0f - ad);
        const float gm = expf(1.0f - 2.0f * ad);
        const float ig = 1.0f / gm;
        const float coef = 1.0f / (3.14159265358979323846f * gm);

        // ========== glimpse phase 1: t1T[gw][h] = sum_w Fw[gw][w]*img[h][w] ==========
        const int fwr = t >> 2;              // gw row this thread fills
        const int fwc = (t & 3) * 8;         // col offset within 32-chunk
        const float rcw = cw + dl * ((float)fwr - 31.5f);
        float rsW = 0.f;

        const float* imgp = imgs + (size_t)(b * 2 + (step & 1)) * (IMG * IMG);
        int rowA[8], coA[8];
        float4 pf[8];
        #pragma unroll
        for (int q = 0; q < 8; ++q) {
            const int c = q * 256 + t;
            rowA[q] = c >> 3;
            coA[q]  = (c & 7) * 4;
            pf[q] = *(const float4*)&imgp[rowA[q] * IMG + coA[q]];
        }
        f32x4 acc[4][4];
        #pragma unroll
        for (int mi = 0; mi < 4; ++mi)
            #pragma unroll
            for (int ni = 0; ni < 4; ++ni) acc[mi][ni] = (f32x4)(0.f);

        for (int ks = 0; ks < 8; ++ks) {
            __syncthreads();
            #pragma unroll
            for (int q = 0; q < 8; ++q) {
                float f[4] = {pf[q].x, pf[q].y, pf[q].z, pf[q].w};
                u16 hh[4], ll[4];
                #pragma unroll
                for (int j = 0; j < 4; ++j) {
                    hh[j] = f2bf(f[j]);
                    ll[j] = f2bf(f[j] - bf2f(hh[j]));
                }
                *(ushort4*)&AstH[rowA[q] * SP + coA[q]] = make_ushort4(hh[0], hh[1], hh[2], hh[3]);
                *(ushort4*)&AstL[rowA[q] * SP + coA[q]] = make_ushort4(ll[0], ll[1], ll[2], ll[3]);
            }
            {
                u16 hh[8], ll[8];
                #pragma unroll
                for (int j = 0; j < 8; ++j) {
                    float u = ((float)(ks * 32 + fwc + j) - rcw) * ig;
                    float val = coef / (1.0f + u * u);
                    rsW += val;
                    hh[j] = f2bf(val);
                    ll[j] = f2bf(val - bf2f(hh[j]));
                }
                *(ushort4*)&FwcH[fwr * SP + fwc]     = make_ushort4(hh[0], hh[1], hh[2], hh[3]);
                *(ushort4*)&FwcH[fwr * SP + fwc + 4] = make_ushort4(hh[4], hh[5], hh[6], hh[7]);
                *(ushort4*)&FwcL[fwr * SP + fwc]     = make_ushort4(ll[0], ll[1], ll[2], ll[3]);
                *(ushort4*)&FwcL[fwr * SP + fwc + 4] = make_ushort4(ll[4], ll[5], ll[6], ll[7]);
            }
            __syncthreads();
            if (ks < 7) {
                #pragma unroll
                for (int q = 0; q < 8; ++q)
                    pf[q] = *(const float4*)&imgp[rowA[q] * IMG + (ks + 1) * 32 + coA[q]];
            }
            s16x8 ah[4], al[4], bh[4], bl[4];
            #pragma unroll
            for (int mi = 0; mi < 4; ++mi) {
                const int r = mi * 16 + fr;
                ah[mi] = *(const s16x8*)&FwcH[r * SP + kg * 8];
                al[mi] = *(const s16x8*)&FwcL[r * SP + kg * 8];
            }
            #pragma unroll
            for (int ni = 0; ni < 4; ++ni) {
                const int r = wv * 64 + ni * 16 + fr;
                bh[ni] = *(const s16x8*)&AstH[r * SP + kg * 8];
                bl[ni] = *(const s16x8*)&AstL[r * SP + kg * 8];
            }
            #pragma unroll
            for (int mi = 0; mi < 4; ++mi)
                #pragma unroll
                for (int ni = 0; ni < 4; ++ni) {
                    acc[mi][ni] = __builtin_amdgcn_mfma_f32_16x16x32_bf16(ah[mi], bh[ni], acc[mi][ni], 0, 0, 0);
                    acc[mi][ni] = __builtin_amdgcn_mfma_f32_16x16x32_bf16(ah[mi], bl[ni], acc[mi][ni], 0, 0, 0);
                    acc[mi][ni] = __builtin_amdgcn_mfma_f32_16x16x32_bf16(al[mi], bh[ni], acc[mi][ni], 0, 0, 0);
                }
        }
        // invW reduce (4 consecutive lanes per row) and scale accumulators
        rsW += __shfl_xor(rsW, 1, 64);
        rsW += __shfl_xor(rsW, 2, 64);
        if ((t & 3) == 0) invW[fwr] = 1.0f / (rsW + 1e-4f);
        __syncthreads();
        #pragma unroll
        for (int mi = 0; mi < 4; ++mi) {
            float w4[4];
            #pragma unroll
            for (int r = 0; r < 4; ++r) w4[r] = invW[mi * 16 + kg * 4 + r];
            #pragma unroll
            for (int ni = 0; ni < 4; ++ni)
                #pragma unroll
                for (int r = 0; r < 4; ++r) acc[mi][ni][r] *= w4[r];
        }

        // ========== glimpse phase 2: x[gh][gw] = invA[gh]*sum_h Fh[gh][h]*t1T[gw][h] ==========
        f32x4 xacc[4];
        #pragma unroll
        for (int ni = 0; ni < 4; ++ni) xacc[ni] = (f32x4)(0.f);
        const int fhr = t >> 2;              // gh row this thread fills
        const int fhc = (t & 3) * 16;        // col offset within 64-chunk
        const float rch = ch + dl * ((float)fhr - 31.5f);
        float rsA = 0.f;

        for (int p = 0; p < 4; ++p) {
            __syncthreads();
            #pragma unroll
            for (int blk = 0; blk < 4; ++blk) {
                u16 hh[4], ll[4];
                #pragma unroll
                for (int j = 0; j < 4; ++j) {
                    float u = ((float)(p * 64 + fhc + blk * 4 + j) - rch) * ig;
                    float val = coef / (1.0f + u * u);
                    rsA += val;
                    hh[j] = f2bf(val);
                    ll[j] = f2bf(val - bf2f(hh[j]));
                }
                *(ushort4*)&FhcH[fhr * TP + fhc + blk * 4] = make_ushort4(hh[0], hh[1], hh[2], hh[3]);
                *(ushort4*)&FhcL[fhr * TP + fhc + blk * 4] = make_ushort4(ll[0], ll[1], ll[2], ll[3]);
            }
            if (wv == p) {
                #pragma unroll
                for (int mi = 0; mi < 4; ++mi)
                    #pragma unroll
                    for (int ni = 0; ni < 4; ++ni)
                        #pragma unroll
                        for (int r = 0; r < 4; ++r) {
                            const int row = mi * 16 + kg * 4 + r;   // gw
                            const int col = ni * 16 + fr;           // local h
                            float v = acc[mi][ni][r];
                            u16 hv = f2bf(v);
                            t1TH[row * TP + col] = hv;
                            t1TL[row * TP + col] = f2bf(v - bf2f(hv));
                        }
            }
            __syncthreads();
            #pragma unroll
            for (int k2 = 0; k2 < 2; ++k2) {
                const int ra = wv * 16 + fr;
                s16x8 a2h = *(const s16x8*)&FhcH[ra * TP + k2 * 32 + kg * 8];
                s16x8 a2l = *(const s16x8*)&FhcL[ra * TP + k2 * 32 + kg * 8];
                #pragma unroll
                for (int ni = 0; ni < 4; ++ni) {
                    const int rb = ni * 16 + fr;
                    s16x8 b2h = *(const s16x8*)&t1TH[rb * TP + k2 * 32 + kg * 8];
                    s16x8 b2l = *(const s16x8*)&t1TL[rb * TP + k2 * 32 + kg * 8];
                    xacc[ni] = __builtin_amdgcn_mfma_f32_16x16x32_bf16(a2h, b2h, xacc[ni], 0, 0, 0);
                    xacc[ni] = __builtin_amdgcn_mfma_f32_16x16x32_bf16(a2h, b2l, xacc[ni], 0, 0, 0);
                    xacc[ni] = __builtin_amdgcn_mfma_f32_16x16x32_bf16(a2l, b2h, xacc[ni], 0, 0, 0);
                }
            }
        }
        // invA reduce + x write (hi/lo into xcat)
        rsA += __shfl_xor(rsA, 1, 64);
        rsA += __shfl_xor(rsA, 2, 64);
        if ((t & 3) == 0) invA[fhr] = 1.0f / (rsA + 1e-4f);
        __syncthreads();
        {
            float ia[4];
            #pragma unroll
            for (int r = 0; r < 4; ++r) ia[r] = invA[wv * 16 + kg * 4 + r];
            u16* xho = xcat_hi + (size_t)b * KTOT;
            u16* xlo = xcat_lo + (size_t)b * KTOT;
            #pragma unroll
            for (int ni = 0; ni < 4; ++ni) {
                const int col = ni * 16 + fr;
                #pragma unroll
                for (int r = 0; r < 4; ++r) {
                    float v = xacc[ni][r] * ia[r];
                    u16 hv = f2bf(v);
                    const int o = (wv * 16 + kg * 4 + r) * GSZ + col;
                    xho[o] = hv;
                    xlo[o] = f2bf(v - bf2f(hv));
                }
            }
        }
        gridbar(bar, 2 * step + 1);

        // ================= G phase: gates GEMM (split-K) =================
        {
            const int mb = b & 1;
            const int nb = (b >> 1) & 15;
            const int kc = b >> 5;
            const int m0 = mb * 128, n0 = nb * 128, k0 = kc * KCHUNK;
            const int wm = wv >> 1, wn = wv & 1;

            const u16* srcs[8];
            u16* dsts[8];
            #pragma unroll
            for (int q = 0; q < 8; ++q) {
                const int idx = ((q * 256 + t) & 511);
                const int row = idx >> 2;
                const int ko = (idx & 3) * 8;
                const int mat = q >> 1;
                const u16* gbase;
                if (mat == 0)      gbase = xcat_hi + (size_t)(m0 + row) * KTOT;
                else if (mat == 1) gbase = xcat_lo + (size_t)(m0 + row) * KTOT;
                else if (mat == 2) gbase = wc_hi + (size_t)(n0 + row) * KTOT;
                else               gbase = wc_lo + (size_t)(n0 + row) * KTOT;
                srcs[q] = gbase + k0 + ko;
                dsts[q] = &gsm[mat][row][ko];
            }

            f32x4 gacc[4][4];
            #pragma unroll
            for (int mi = 0; mi < 4; ++mi)
                #pragma unroll
                for (int ni = 0; ni < 4; ++ni) gacc[mi][ni] = (f32x4)(0.f);

            s16x8 ld[8];
            #pragma unroll
            for (int q = 0; q < 8; ++q) ld[q] = *(const s16x8*)(srcs[q]);

            for (int ks = 0; ks < KSTEPS; ++ks) {
                __syncthreads();
                #pragma unroll
                for (int q = 0; q < 8; ++q) {
                    *(s16x8*)(dsts[q]) = ld[q];
                    srcs[q] += 32;
                }
                __syncthreads();
                if (ks + 1 < KSTEPS) {
                    #pragma unroll
                    for (int q = 0; q < 8; ++q) ld[q] = *(const s16x8*)(srcs[q]);
                }
                s16x8 ah[4], al[4], bh[4], bl[4];
                #pragma unroll
                for (int mi = 0; mi < 4; ++mi) {
                    const int r = wm * 64 + mi * 16 + fr;
                    ah[mi] = *(const s16x8*)&gsm[0][r][kg * 8];
                    al[mi] = *(const s16x8*)&gsm[1][r][kg * 8];
                }
                #pragma unroll
                for (int ni = 0; ni < 4; ++ni) {
                    const int r = wn * 64 + ni * 16 + fr;
                    bh[ni] = *(const s16x8*)&gsm[2][r][kg * 8];
                    bl[ni] = *(const s16x8*)&gsm[3][r][kg * 8];
                }
                #pragma unroll
                for (int mi = 0; mi < 4; ++mi)
                    #pragma unroll
                    for (int ni = 0; ni < 4; ++ni) {
                        gacc[mi][ni] = __builtin_amdgcn_mfma_f32_16x16x32_bf16(ah[mi], bh[ni], gacc[mi][ni], 0, 0, 0);
                        gacc[mi][ni] = __builtin_amdgcn_mfma_f32_16x16x32_bf16(ah[mi], bl[ni], gacc[mi][ni], 0, 0, 0);
                        gacc[mi][ni] = __builtin_amdgcn_mfma_f32_16x16x32_bf16(al[mi], bh[ni], gacc[mi][ni], 0, 0, 0);
                    }
            }

            float* pp = part + ((size_t)kc << 19);
            #pragma unroll
            for (int mi = 0; mi < 4; ++mi) {
                const int mbase = m0 + wm * 64 + mi * 16 + kg * 4;
                #pragma unroll
                for (int ni = 0; ni < 4; ++ni) {
                    const int col = n0 + wn * 64 + ni * 16 + fr;
                    #pragma unroll
                    for (int r = 0; r < 4; ++r)
                        pp[(size_t)(mbase + r) * 2048 + col] = gacc[mi][ni][r];
                }
            }
        }
        gridbar(bar, 2 * step + 2);
    }

    // ================= final LSTM update -> out =================
    #pragma unroll
    for (int half = 0; half < 2; ++half) {
        const int u = t + half * 256;
        float gi = b_ih[u] + b_hh[u];
        float gf = b_ih[HID + u] + b_hh[HID + u];
        float gg = b_ih[2 * HID + u] + b_hh[2 * HID + u];
        float go = b_ih[3 * HID + u] + b_hh[3 * HID + u];
        const float* pb = part + (size_t)b * 2048;
        #pragma unroll
        for (int kc = 0; kc < SPLITK; ++kc) {
            const float* p = pb + (size_t)kc * (256 * 2048);
            gi += p[u];
            gf += p[HID + u];
            gg += p[2 * HID + u];
            go += p[3 * HID + u];
        }
        float co = half ? cx1 : cx0;
        float c = sigm(gf) * co + sigm(gi) * tanhf(gg);
        float h = sigm(go) * tanhf(c);
        out[(size_t)b * HID + u] = h;
    }
}

extern "C" void kernel_launch(void* const* d_in, const int* in_sizes, int n_in,
                              void* d_out, int out_size, void* d_ws, size_t ws_size,
                              hipStream_t stream) {
    const float* imgs = (const float*)d_in[0];
    const float* W_ih = (const float*)d_in[1];
    const float* W_hh = (const float*)d_in[2];
    const float* b_ih = (const float*)d_in[3];
    const float* b_hh = (const float*)d_in[4];
    const float* W_g  = (const float*)d_in[5];
    const float* b_g  = (const float*)d_in[6];
    float* out = (float*)d_out;

    char* w = (char*)d_ws;
    int* bar       = (int*)w;    w += 4096;                     // 257 ints used
    u16* xcat_hi   = (u16*)w;    w += (size_t)NB * KTOT * 2;
    u16* xcat_lo   = (u16*)w;    w += (size_t)NB * KTOT * 2;
    u16* wc_hi     = (u16*)w;    w += (size_t)2048 * KTOT * 2;
    u16* wc_lo     = (u16*)w;    w += (size_t)2048 * KTOT * 2;
    float* part    = (float*)w;  w += (size_t)SPLITK * NB * 2048 * 4;

    // barrier state must start at 0 every call (ws is poisoned once, not re-poisoned)
    hipMemsetAsync(bar, 0, 4096, stream);

    k_all<<<NB, 256, 0, stream>>>(imgs, W_ih, W_hh, b_ih, b_hh, W_g, b_g,
                                  bar, wc_hi, wc_lo, xcat_hi, xcat_lo, part, out);
}

// Round 8
// 1879.479 us; speedup vs baseline: 1.7050x; 1.7050x over previous
//
#include <hip/hip_runtime.h>
#include <math.h>

#define NB 256
#define IMG 256
#define GSZ 64
#define HID 512
#define NSTEP 16
#define KTOT 4608            // 4096 (x) + 512 (Hx)
#define SPLITK 8
#define KCHUNK 576           // KTOT / SPLITK
#define KSTEPS 18            // KCHUNK / 32
#define SP 40                // img-stage / Fw-chunk pitch (u16)
#define TP 72                // t1T / Fh chunk pitch (u16)

typedef unsigned short u16;
typedef __attribute__((ext_vector_type(8))) short s16x8;   // 8 bf16
typedef __attribute__((ext_vector_type(4))) float f32x4;

__device__ inline u16 f2bf(float f) {           // round-to-nearest-even bf16
    unsigned u = __float_as_uint(f);
    unsigned r = u + 0x7fffu + ((u >> 16) & 1u);
    return (u16)(r >> 16);
}
__device__ inline float bf2f(u16 h) { return __uint_as_float((unsigned)h << 16); }
__device__ inline float sigm(float v) { return 1.0f / (1.0f + expf(-v)); }

// software grid barrier: bar[0]=release gen, bar[1..256]=per-block arrive gen.
// All NB blocks resident (LDS 52KB -> 3 blk/CU; launch_bounds(256,2) -> >=2 blk/CU).
// Spin is RELAXED (no per-poll cache invalidate); after observing the target
// generation, ONE acquire load of the same flag forms the synchronizes-with
// edge with the remote RELEASE store (r7's fence-relay lacked this edge ->
// stale data; r6's per-poll acquire invalidated L2 continuously -> 3.5ms).
__device__ inline void gridbar(int* bar, int gen) {
    __syncthreads();
    const int b = blockIdx.x, t = threadIdx.x;
    if (b == 0) {
        if (t > 0) {          // thread t watches block t's arrive flag
            while (__hip_atomic_load(&bar[1 + t], __ATOMIC_RELAXED,
                                     __HIP_MEMORY_SCOPE_AGENT) < gen)
                __builtin_amdgcn_s_sleep(4);
            (void)__hip_atomic_load(&bar[1 + t], __ATOMIC_ACQUIRE,
                                    __HIP_MEMORY_SCOPE_AGENT);   // HB: block t -> here
        }
        __syncthreads();      // HB: watchers -> t0
        if (t == 0)
            __hip_atomic_store(&bar[0], gen, __ATOMIC_RELEASE,
                               __HIP_MEMORY_SCOPE_AGENT);        // carries all blocks' writes
    } else {
        if (t == 0) {
            __hip_atomic_store(&bar[1 + b], gen, __ATOMIC_RELEASE,
                               __HIP_MEMORY_SCOPE_AGENT);        // publishes this block's writes
            while (__hip_atomic_load(&bar[0], __ATOMIC_RELAXED,
                                     __HIP_MEMORY_SCOPE_AGENT) < gen)
                __builtin_amdgcn_s_sleep(4);
            (void)__hip_atomic_load(&bar[0], __ATOMIC_ACQUIRE,
                                    __HIP_MEMORY_SCOPE_AGENT);   // HB: block0 relay -> here
        }
        __syncthreads();      // HB: t0 -> whole block
    }
}

__global__ __launch_bounds__(256, 2) void k_all(
    const float* __restrict__ imgs, const float* __restrict__ W_ih,
    const float* __restrict__ W_hh, const float* __restrict__ b_ih,
    const float* __restrict__ b_hh, const float* __restrict__ W_g,
    const float* __restrict__ b_g,
    int* __restrict__ bar,
    u16* __restrict__ wc_hi, u16* __restrict__ wc_lo,
    u16* __restrict__ xcat_hi, u16* __restrict__ xcat_lo,
    float* __restrict__ part, float* __restrict__ out)
{
    // 51,200 B overlaid static LDS (+ small scratch) -- fits default 64 KB
    __shared__ __align__(16) u16 sm[25600];
    __shared__ float invW[64];
    __shared__ float invA[64];
    __shared__ float red[12];
    // phase-1 overlay
    u16* AstH = sm;            // [256][SP] img chunk hi
    u16* AstL = sm + 10240;    // [256][SP] img chunk lo
    u16* FwcH = sm + 20480;    // [64][SP]  Fw chunk hi
    u16* FwcL = sm + 23040;    // [64][SP]  Fw chunk lo
    // phase-2 overlay
    u16* t1TH = sm;            // [64][TP]  t1T chunk hi
    u16* t1TL = sm + 4608;
    u16* FhcH = sm + 9216;     // [64][TP]  Fh chunk hi
    u16* FhcL = sm + 13824;
    // G-phase overlay
    u16 (*gsm)[128][40] = (u16 (*)[128][40])sm;

    const int b = blockIdx.x, t = threadIdx.x;
    const int lane = t & 63, wv = t >> 6;
    const int fr = lane & 15, kg = lane >> 4;

    // persistent LSTM state: units t and t+256 of batch b
    float hx0 = 0.f, hx1 = 0.f, cx0 = 0.f, cx1 = 0.f;

    // G-phase tiling (constant per block)
    const int mbG = b & 1;
    const int nbG = (b >> 1) & 15;
    const int kcG = b >> 5;
    const int m0G = mbG * 128, n0G = nbG * 128, k0G = kcG * KCHUNK;
    const int wmG = wv >> 1, wnG = wv & 1;
    const u16* gsrc0[8];       // start-of-chunk source pointers
    u16* gdst[8];
    #pragma unroll
    for (int q = 0; q < 8; ++q) {
        const int idx = ((q * 256 + t) & 511);
        const int row = idx >> 2;
        const int ko = (idx & 3) * 8;
        const int mat = q >> 1;
        const u16* gbase;
        if (mat == 0)      gbase = xcat_hi + (size_t)(m0G + row) * KTOT;
        else if (mat == 1) gbase = xcat_lo + (size_t)(m0G + row) * KTOT;
        else if (mat == 2) gbase = wc_hi + (size_t)(n0G + row) * KTOT;
        else               gbase = wc_lo + (size_t)(n0G + row) * KTOT;
        gsrc0[q] = gbase + k0G + ko;
        gdst[q] = &gsm[mat][row][ko];
    }

    // ---------- weight split phase (wc = [W_ih | W_hh] hi/lo) ----------
    {
        const int nchunk = 2048 * KTOT / 4;      // 2,359,296
        for (int c = b * 256 + t; c < nchunk; c += 65536) {
            const int j = c / (KTOT / 4);
            const int k = (c - j * (KTOT / 4)) * 4;
            float4 v;
            if (k < 4096) v = *(const float4*)&W_ih[(size_t)j * 4096 + k];
            else          v = *(const float4*)&W_hh[(size_t)j * 512 + (k - 4096)];
            float f[4] = {v.x, v.y, v.z, v.w};
            u16 hi[4], lo[4];
            #pragma unroll
            for (int i = 0; i < 4; ++i) {
                hi[i] = f2bf(f[i]);
                lo[i] = f2bf(f[i] - bf2f(hi[i]));
            }
            const size_t o = (size_t)j * KTOT + k;
            *(ushort4*)&wc_hi[o] = make_ushort4(hi[0], hi[1], hi[2], hi[3]);
            *(ushort4*)&wc_lo[o] = make_ushort4(lo[0], lo[1], lo[2], lo[3]);
        }
    }
    // first wc read is in G(0), after the first grid barrier

    for (int step = 0; step < NSTEP; ++step) {
        // ========== LSTM update from previous step's partials ==========
        if (step == 0) {
            const size_t o = (size_t)b * KTOT + 4096 + t;
            xcat_hi[o] = 0;       xcat_lo[o] = 0;
            xcat_hi[o + 256] = 0; xcat_lo[o + 256] = 0;
        } else {
            #pragma unroll
            for (int half = 0; half < 2; ++half) {
                const int u = t + half * 256;
                float gi = b_ih[u] + b_hh[u];
                float gf = b_ih[HID + u] + b_hh[HID + u];
                float gg = b_ih[2 * HID + u] + b_hh[2 * HID + u];
                float go = b_ih[3 * HID + u] + b_hh[3 * HID + u];
                const float* pb = part + (size_t)b * 2048;
                #pragma unroll
                for (int kc = 0; kc < SPLITK; ++kc) {
                    const float* p = pb + (size_t)kc * (256 * 2048);
                    gi += p[u];
                    gf += p[HID + u];
                    gg += p[2 * HID + u];
                    go += p[3 * HID + u];
                }
                float co = half ? cx1 : cx0;
                float c = sigm(gf) * co + sigm(gi) * tanhf(gg);
                float h = sigm(go) * tanhf(c);
                if (half) { cx1 = c; hx1 = h; } else { cx0 = c; hx0 = h; }
                u16 hh = f2bf(h);
                xcat_hi[(size_t)b * KTOT + 4096 + u] = hh;
                xcat_lo[(size_t)b * KTOT + 4096 + u] = f2bf(h - bf2f(hh));
            }
        }
        // ========== params: gp = tanh(Hx @ W_g^T + b_g) ==========
        float s0 = hx0 * W_g[t] + hx1 * W_g[t + 256];
        float s1 = hx0 * W_g[HID + t] + hx1 * W_g[HID + t + 256];
        float s2 = hx0 * W_g[2 * HID + t] + hx1 * W_g[2 * HID + t + 256];
        for (int off = 32; off; off >>= 1) {
            s0 += __shfl_xor(s0, off, 64);
            s1 += __shfl_xor(s1, off, 64);
            s2 += __shfl_xor(s2, off, 64);
        }
        __syncthreads();
        if (lane == 0) { red[wv * 3 + 0] = s0; red[wv * 3 + 1] = s1; red[wv * 3 + 2] = s2; }
        __syncthreads();
        s0 = red[0] + red[3] + red[6] + red[9];
        s1 = red[1] + red[4] + red[7] + red[10];
        s2 = red[2] + red[5] + red[8] + red[11];
        const float g0 = tanhf(s0 + b_g[0]);
        const float g1 = tanhf(s1 + b_g[1]);
        const float g2 = tanhf(s2 + b_g[2]);
        const float ad = fabsf(g2);
        const float ch = 127.5f * (g0 + 1.0f);
        const float cw = 127.5f * (g1 + 1.0f);
        const float dl = 4.0f * (1.0f - ad);
        const float gm = expf(1.0f - 2.0f * ad);
        const float ig = 1.0f / gm;
        const float coef = 1.0f / (3.14159265358979323846f * gm);

        // ========== glimpse phase 1: t1T[gw][h] = sum_w Fw[gw][w]*img[h][w] ==========
        const int fwr = t >> 2;              // gw row this thread fills
        const int fwc = (t & 3) * 8;         // col offset within 32-chunk
        const float rcw = cw + dl * ((float)fwr - 31.5f);
        float rsW = 0.f;

        const float* imgp = imgs + (size_t)(b * 2 + (step & 1)) * (IMG * IMG);
        int rowA[8], coA[8];
        float4 pf[8];
        #pragma unroll
        for (int q = 0; q < 8; ++q) {
            const int c = q * 256 + t;
            rowA[q] = c >> 3;
            coA[q]  = (c & 7) * 4;
            pf[q] = *(const float4*)&imgp[rowA[q] * IMG + coA[q]];
        }
        f32x4 acc[4][4];
        #pragma unroll
        for (int mi = 0; mi < 4; ++mi)
            #pragma unroll
            for (int ni = 0; ni < 4; ++ni) acc[mi][ni] = (f32x4)(0.f);

        for (int ks = 0; ks < 8; ++ks) {
            __syncthreads();
            #pragma unroll
            for (int q = 0; q < 8; ++q) {
                float f[4] = {pf[q].x, pf[q].y, pf[q].z, pf[q].w};
                u16 hh[4], ll[4];
                #pragma unroll
                for (int j = 0; j < 4; ++j) {
                    hh[j] = f2bf(f[j]);
                    ll[j] = f2bf(f[j] - bf2f(hh[j]));
                }
                *(ushort4*)&AstH[rowA[q] * SP + coA[q]] = make_ushort4(hh[0], hh[1], hh[2], hh[3]);
                *(ushort4*)&AstL[rowA[q] * SP + coA[q]] = make_ushort4(ll[0], ll[1], ll[2], ll[3]);
            }
            {
                u16 hh[8], ll[8];
                #pragma unroll
                for (int j = 0; j < 8; ++j) {
                    float u = ((float)(ks * 32 + fwc + j) - rcw) * ig;
                    float val = coef / (1.0f + u * u);
                    rsW += val;
                    hh[j] = f2bf(val);
                    ll[j] = f2bf(val - bf2f(hh[j]));
                }
                *(ushort4*)&FwcH[fwr * SP + fwc]     = make_ushort4(hh[0], hh[1], hh[2], hh[3]);
                *(ushort4*)&FwcH[fwr * SP + fwc + 4] = make_ushort4(hh[4], hh[5], hh[6], hh[7]);
                *(ushort4*)&FwcL[fwr * SP + fwc]     = make_ushort4(ll[0], ll[1], ll[2], ll[3]);
                *(ushort4*)&FwcL[fwr * SP + fwc + 4] = make_ushort4(ll[4], ll[5], ll[6], ll[7]);
            }
            __syncthreads();
            if (ks < 7) {
                #pragma unroll
                for (int q = 0; q < 8; ++q)
                    pf[q] = *(const float4*)&imgp[rowA[q] * IMG + (ks + 1) * 32 + coA[q]];
            }
            s16x8 ah[4], al[4], bh[4], bl[4];
            #pragma unroll
            for (int mi = 0; mi < 4; ++mi) {
                const int r = mi * 16 + fr;
                ah[mi] = *(const s16x8*)&FwcH[r * SP + kg * 8];
                al[mi] = *(const s16x8*)&FwcL[r * SP + kg * 8];
            }
            #pragma unroll
            for (int ni = 0; ni < 4; ++ni) {
                const int r = wv * 64 + ni * 16 + fr;
                bh[ni] = *(const s16x8*)&AstH[r * SP + kg * 8];
                bl[ni] = *(const s16x8*)&AstL[r * SP + kg * 8];
            }
            #pragma unroll
            for (int mi = 0; mi < 4; ++mi)
                #pragma unroll
                for (int ni = 0; ni < 4; ++ni) {
                    acc[mi][ni] = __builtin_amdgcn_mfma_f32_16x16x32_bf16(ah[mi], bh[ni], acc[mi][ni], 0, 0, 0);
                    acc[mi][ni] = __builtin_amdgcn_mfma_f32_16x16x32_bf16(ah[mi], bl[ni], acc[mi][ni], 0, 0, 0);
                    acc[mi][ni] = __builtin_amdgcn_mfma_f32_16x16x32_bf16(al[mi], bh[ni], acc[mi][ni], 0, 0, 0);
                }
        }
        // invW reduce (4 consecutive lanes per row) and scale accumulators
        rsW += __shfl_xor(rsW, 1, 64);
        rsW += __shfl_xor(rsW, 2, 64);
        if ((t & 3) == 0) invW[fwr] = 1.0f / (rsW + 1e-4f);
        __syncthreads();
        #pragma unroll
        for (int mi = 0; mi < 4; ++mi) {
            float w4[4];
            #pragma unroll
            for (int r = 0; r < 4; ++r) w4[r] = invW[mi * 16 + kg * 4 + r];
            #pragma unroll
            for (int ni = 0; ni < 4; ++ni)
                #pragma unroll
                for (int r = 0; r < 4; ++r) acc[mi][ni][r] *= w4[r];
        }

        // ========== glimpse phase 2: x[gh][gw] = invA[gh]*sum_h Fh[gh][h]*t1T[gw][h] ==========
        f32x4 xacc[4];
        #pragma unroll
        for (int ni = 0; ni < 4; ++ni) xacc[ni] = (f32x4)(0.f);
        const int fhr = t >> 2;              // gh row this thread fills
        const int fhc = (t & 3) * 16;        // col offset within 64-chunk
        const float rch = ch + dl * ((float)fhr - 31.5f);
        float rsA = 0.f;

        for (int p = 0; p < 4; ++p) {
            __syncthreads();
            #pragma unroll
            for (int blk = 0; blk < 4; ++blk) {
                u16 hh[4], ll[4];
                #pragma unroll
                for (int j = 0; j < 4; ++j) {
                    float u = ((float)(p * 64 + fhc + blk * 4 + j) - rch) * ig;
                    float val = coef / (1.0f + u * u);
                    rsA += val;
                    hh[j] = f2bf(val);
                    ll[j] = f2bf(val - bf2f(hh[j]));
                }
                *(ushort4*)&FhcH[fhr * TP + fhc + blk * 4] = make_ushort4(hh[0], hh[1], hh[2], hh[3]);
                *(ushort4*)&FhcL[fhr * TP + fhc + blk * 4] = make_ushort4(ll[0], ll[1], ll[2], ll[3]);
            }
            if (wv == p) {
                #pragma unroll
                for (int mi = 0; mi < 4; ++mi)
                    #pragma unroll
                    for (int ni = 0; ni < 4; ++ni)
                        #pragma unroll
                        for (int r = 0; r < 4; ++r) {
                            const int row = mi * 16 + kg * 4 + r;   // gw
                            const int col = ni * 16 + fr;           // local h
                            float v = acc[mi][ni][r];
                            u16 hv = f2bf(v);
                            t1TH[row * TP + col] = hv;
                            t1TL[row * TP + col] = f2bf(v - bf2f(hv));
                        }
            }
            __syncthreads();
            #pragma unroll
            for (int k2 = 0; k2 < 2; ++k2) {
                const int ra = wv * 16 + fr;
                s16x8 a2h = *(const s16x8*)&FhcH[ra * TP + k2 * 32 + kg * 8];
                s16x8 a2l = *(const s16x8*)&FhcL[ra * TP + k2 * 32 + kg * 8];
                #pragma unroll
                for (int ni = 0; ni < 4; ++ni) {
                    const int rb = ni * 16 + fr;
                    s16x8 b2h = *(const s16x8*)&t1TH[rb * TP + k2 * 32 + kg * 8];
                    s16x8 b2l = *(const s16x8*)&t1TL[rb * TP + k2 * 32 + kg * 8];
                    xacc[ni] = __builtin_amdgcn_mfma_f32_16x16x32_bf16(a2h, b2h, xacc[ni], 0, 0, 0);
                    xacc[ni] = __builtin_amdgcn_mfma_f32_16x16x32_bf16(a2h, b2l, xacc[ni], 0, 0, 0);
                    xacc[ni] = __builtin_amdgcn_mfma_f32_16x16x32_bf16(a2l, b2h, xacc[ni], 0, 0, 0);
                }
            }
        }
        // invA reduce + x write (hi/lo into xcat)
        rsA += __shfl_xor(rsA, 1, 64);
        rsA += __shfl_xor(rsA, 2, 64);
        if ((t & 3) == 0) invA[fhr] = 1.0f / (rsA + 1e-4f);
        __syncthreads();
        {
            float ia[4];
            #pragma unroll
            for (int r = 0; r < 4; ++r) ia[r] = invA[wv * 16 + kg * 4 + r];
            u16* xho = xcat_hi + (size_t)b * KTOT;
            u16* xlo = xcat_lo + (size_t)b * KTOT;
            #pragma unroll
            for (int ni = 0; ni < 4; ++ni) {
                const int col = ni * 16 + fr;
                #pragma unroll
                for (int r = 0; r < 4; ++r) {
                    float v = xacc[ni][r] * ia[r];
                    u16 hv = f2bf(v);
                    const int o = (wv * 16 + kg * 4 + r) * GSZ + col;
                    xho[o] = hv;
                    xlo[o] = f2bf(v - bf2f(hv));
                }
            }
        }

        // prefetch this block's FIRST weight tiles (constant data) into regs;
        // their latency hides under barrier skew. xcat loads must wait for the barrier.
        s16x8 gld[8];
        #pragma unroll
        for (int q = 4; q < 8; ++q) gld[q] = *(const s16x8*)(gsrc0[q]);

        gridbar(bar, 2 * step + 1);

        // ================= G phase: gates GEMM (split-K) =================
        {
            const u16* srcs[8];
            #pragma unroll
            for (int q = 0; q < 8; ++q) srcs[q] = gsrc0[q];
            #pragma unroll
            for (int q = 0; q < 4; ++q) gld[q] = *(const s16x8*)(srcs[q]);

            f32x4 gacc[4][4];
            #pragma unroll
            for (int mi = 0; mi < 4; ++mi)
                #pragma unroll
                for (int ni = 0; ni < 4; ++ni) gacc[mi][ni] = (f32x4)(0.f);

            for (int ks = 0; ks < KSTEPS; ++ks) {
                __syncthreads();
                #pragma unroll
                for (int q = 0; q < 8; ++q) {
                    *(s16x8*)(gdst[q]) = gld[q];
                    srcs[q] += 32;
                }
                __syncthreads();
                if (ks + 1 < KSTEPS) {
                    #pragma unroll
                    for (int q = 0; q < 8; ++q) gld[q] = *(const s16x8*)(srcs[q]);
                }
                s16x8 ah[4], al[4], bh[4], bl[4];
                #pragma unroll
                for (int mi = 0; mi < 4; ++mi) {
                    const int r = wmG * 64 + mi * 16 + fr;
                    ah[mi] = *(const s16x8*)&gsm[0][r][kg * 8];
                    al[mi] = *(const s16x8*)&gsm[1][r][kg * 8];
                }
                #pragma unroll
                for (int ni = 0; ni < 4; ++ni) {
                    const int r = wnG * 64 + ni * 16 + fr;
                    bh[ni] = *(const s16x8*)&gsm[2][r][kg * 8];
                    bl[ni] = *(const s16x8*)&gsm[3][r][kg * 8];
                }
                #pragma unroll
                for (int mi = 0; mi < 4; ++mi)
                    #pragma unroll
                    for (int ni = 0; ni < 4; ++ni) {
                        gacc[mi][ni] = __builtin_amdgcn_mfma_f32_16x16x32_bf16(ah[mi], bh[ni], gacc[mi][ni], 0, 0, 0);
                        gacc[mi][ni] = __builtin_amdgcn_mfma_f32_16x16x32_bf16(ah[mi], bl[ni], gacc[mi][ni], 0, 0, 0);
                        gacc[mi][ni] = __builtin_amdgcn_mfma_f32_16x16x32_bf16(al[mi], bh[ni], gacc[mi][ni], 0, 0, 0);
                    }
            }

            float* pp = part + ((size_t)kcG << 19);
            #pragma unroll
            for (int mi = 0; mi < 4; ++mi) {
                const int mbase = m0G + wmG * 64 + mi * 16 + kg * 4;
                #pragma unroll
                for (int ni = 0; ni < 4; ++ni) {
                    const int col = n0G + wnG * 64 + ni * 16 + fr;
                    #pragma unroll
                    for (int r = 0; r < 4; ++r)
                        pp[(size_t)(mbase + r) * 2048 + col] = gacc[mi][ni][r];
                }
            }
        }
        gridbar(bar, 2 * step + 2);
    }

    // ================= final LSTM update -> out =================
    #pragma unroll
    for (int half = 0; half < 2; ++half) {
        const int u = t + half * 256;
        float gi = b_ih[u] + b_hh[u];
        float gf = b_ih[HID + u] + b_hh[HID + u];
        float gg = b_ih[2 * HID + u] + b_hh[2 * HID + u];
        float go = b_ih[3 * HID + u] + b_hh[3 * HID + u];
        const float* pb = part + (size_t)b * 2048;
        #pragma unroll
        for (int kc = 0; kc < SPLITK; ++kc) {
            const float* p = pb + (size_t)kc * (256 * 2048);
            gi += p[u];
            gf += p[HID + u];
            gg += p[2 * HID + u];
            go += p[3 * HID + u];
        }
        float co = half ? cx1 : cx0;
        float c = sigm(gf) * co + sigm(gi) * tanhf(gg);
        float h = sigm(go) * tanhf(c);
        out[(size_t)b * HID + u] = h;
    }
}

extern "C" void kernel_launch(void* const* d_in, const int* in_sizes, int n_in,
                              void* d_out, int out_size, void* d_ws, size_t ws_size,
                              hipStream_t stream) {
    const float* imgs = (const float*)d_in[0];
    const float* W_ih = (const float*)d_in[1];
    const float* W_hh = (const float*)d_in[2];
    const float* b_ih = (const float*)d_in[3];
    const float* b_hh = (const float*)d_in[4];
    const float* W_g  = (const float*)d_in[5];
    const float* b_g  = (const float*)d_in[6];
    float* out = (float*)d_out;

    char* w = (char*)d_ws;
    int* bar       = (int*)w;    w += 4096;                     // 257 ints used
    u16* xcat_hi   = (u16*)w;    w += (size_t)NB * KTOT * 2;
    u16* xcat_lo   = (u16*)w;    w += (size_t)NB * KTOT * 2;
    u16* wc_hi     = (u16*)w;    w += (size_t)2048 * KTOT * 2;
    u16* wc_lo     = (u16*)w;    w += (size_t)2048 * KTOT * 2;
    float* part    = (float*)w;  w += (size_t)SPLITK * NB * 2048 * 4;

    // barrier state must start at 0 every call (ws is poisoned once, not re-poisoned)
    hipMemsetAsync(bar, 0, 4096, stream);

    k_all<<<NB, 256, 0, stream>>>(imgs, W_ih, W_hh, b_ih, b_hh, W_g, b_g,
                                  bar, wc_hi, wc_lo, xcat_hi, xcat_lo, part, out);
}